// Round 13
// baseline (1071.432 us; speedup 1.0000x reference)
//
#include <hip/hip_runtime.h>
#include <math.h>

#define N_NODES 10000
#define L_LEN   256
#define D_DIM   32
#define K_NBR   32
#define NTOT    (N_NODES * L_LEN)
#define EPS_BN  1e-5f

__device__ __forceinline__ float silu_f(float x) {
    return x / (1.0f + expf(-x));
}

// ---------- kernel 1: global sum & sumsq of pop ----------
__global__ void stats_kernel(const float* __restrict__ pop, float* __restrict__ stats) {
    __shared__ float s1[256], s2[256];
    int t = threadIdx.x;
    float a = 0.f, b = 0.f;
    for (int idx = blockIdx.x * 256 + t; idx < NTOT; idx += gridDim.x * 256) {
        float v = pop[idx];
        a += v; b += v * v;
    }
    s1[t] = a; s2[t] = b;
    __syncthreads();
    for (int s = 128; s > 0; s >>= 1) {
        if (t < s) { s1[t] += s1[t + s]; s2[t] += s2[t + s]; }
        __syncthreads();
    }
    if (t == 0) { atomicAdd(&stats[0], s1[0]); atomicAdd(&stats[1], s2[0]); }
}

// ---------- kernel 2: featurize (BN folded to global scalar stats) ----------
__global__ void feat_kernel(const float* __restrict__ pop,
                            const float* __restrict__ conv_w,
                            const float* __restrict__ conv_b,
                            const float* __restrict__ gamma,
                            const float* __restrict__ beta,
                            const float* __restrict__ stats,
                            float* __restrict__ X,
                            float* __restrict__ SQ) {
    __shared__ float row[L_LEN];
    __shared__ float part[256];
    int i = blockIdx.x;
    int t = threadIdx.x;
    row[t] = pop[i * L_LEN + t];
    __syncthreads();
    int d = t & 31, g = t >> 5;
    float M  = stats[0] * (1.0f / NTOT);
    float Vc = stats[1] * (1.0f / NTOT) - M * M;
    float w = conv_w[d], b = conv_b[d];
    float mean = fmaf(w, M, b);
    float var  = w * w * Vc;
    float sc = gamma[d] / sqrtf(var + EPS_BN);
    float bt = beta[d];
    float acc = 0.f;
    int l0 = g * 32;
    #pragma unroll
    for (int l = 0; l < 32; ++l) {
        float y = fmaf(row[l0 + l], w, b);
        float z = fmaf(y - mean, sc, bt);
        acc += silu_f(z);
    }
    part[t] = acc;
    __syncthreads();
    if (t < 32) {
        float s = 0.f;
        #pragma unroll
        for (int gg = 0; gg < 8; ++gg) s += part[gg * 32 + t];
        float xv = s * (1.0f / L_LEN);
        X[i * D_DIM + t] = xv;
        part[t] = xv;
    }
    __syncthreads();
    if (t == 0) {
        float sq = 0.f;
        #pragma unroll
        for (int dd = 0; dd < 32; ++dd) sq += part[dd] * part[dd];
        SQ[i] = sq;
    }
}

// ---------- wave-sorted-list exact top-k insertion ----------
// run: 1 u64/lane, ascending across lanes (lane L = (L+1)-th smallest so far).
__device__ __forceinline__ void insert_top(unsigned long long &run,
                                           unsigned long long key, int lane) {
    unsigned long long kmax = __shfl(run, 63);
    unsigned long long mask = __ballot(key < kmax);
    while (mask) {
        int b = (int)__ffsll(mask) - 1;
        mask &= mask - 1;
        unsigned long long kb = __shfl(key, b);
        if (kb < kmax) {                       // uniform branch (kb,kmax uniform)
            int pos = __popcll(__ballot(run <= kb));
            unsigned long long up = __shfl_up(run, 1);
            run = (lane < pos) ? run : (lane == pos ? kb : up);
            kmax = __shfl(run, 63);
        }
    }
}

// ---------- kernel 3: kNN, 4 queries/wave, zero LDS, zero atomics ----------
// Lane = candidate. Composite key (d2_ukey<<32|idx) => top_k's exact
// value-then-lowest-index semantics. 625 blocks x 256 thr (4 waves x 4 queries).
__global__ __launch_bounds__(256) void knn_wave(const float* __restrict__ X,
                                                const float* __restrict__ SQ,
                                                int* __restrict__ NBR) {
    int lane = threadIdx.x & 63;
    int wv   = threadIdx.x >> 6;
    int q0   = blockIdx.x * 16 + wv * 4;       // 4 queries per wave

    const float4* qr0 = (const float4*)(X + (size_t)(q0 + 0) * D_DIM);
    const float4* qr1 = (const float4*)(X + (size_t)(q0 + 1) * D_DIM);
    const float4* qr2 = (const float4*)(X + (size_t)(q0 + 2) * D_DIM);
    const float4* qr3 = (const float4*)(X + (size_t)(q0 + 3) * D_DIM);
    float sq0 = SQ[q0 + 0], sq1 = SQ[q0 + 1], sq2 = SQ[q0 + 2], sq3 = SQ[q0 + 3];

    unsigned long long run0 = ~0ULL, run1 = ~0ULL, run2 = ~0ULL, run3 = ~0ULL;

    for (int base = 0; base < N_NODES; base += 64) {
        int c = base + lane;
        bool valid = c < N_NODES;
        float4 xr[8];
        const float4* xp = (const float4*)(X + (size_t)c * D_DIM);
        if (valid) {
            #pragma unroll
            for (int i = 0; i < 8; ++i) xr[i] = xp[i];
        } else {
            #pragma unroll
            for (int i = 0; i < 8; ++i) xr[i] = make_float4(0.f, 0.f, 0.f, 0.f);
        }
        float sqc = valid ? SQ[c] : 0.f;

        float a0 = 0.f, a1 = 0.f, a2 = 0.f, a3 = 0.f;
        #pragma unroll
        for (int i = 0; i < 8; ++i) {
            float4 v  = xr[i];
            float4 w0 = qr0[i];                // wave-uniform -> scalar loads
            float4 w1 = qr1[i];
            float4 w2 = qr2[i];
            float4 w3 = qr3[i];
            a0 = fmaf(v.x, w0.x, a0); a0 = fmaf(v.y, w0.y, a0);
            a0 = fmaf(v.z, w0.z, a0); a0 = fmaf(v.w, w0.w, a0);
            a1 = fmaf(v.x, w1.x, a1); a1 = fmaf(v.y, w1.y, a1);
            a1 = fmaf(v.z, w1.z, a1); a1 = fmaf(v.w, w1.w, a1);
            a2 = fmaf(v.x, w2.x, a2); a2 = fmaf(v.y, w2.y, a2);
            a2 = fmaf(v.z, w2.z, a2); a2 = fmaf(v.w, w2.w, a2);
            a3 = fmaf(v.x, w3.x, a3); a3 = fmaf(v.y, w3.y, a3);
            a3 = fmaf(v.z, w3.z, a3); a3 = fmaf(v.w, w3.w, a3);
        }

        #pragma unroll
        for (int qi = 0; qi < 4; ++qi) {
            float sqq = (qi == 0) ? sq0 : (qi == 1) ? sq1 : (qi == 2) ? sq2 : sq3;
            float acc = (qi == 0) ? a0  : (qi == 1) ? a1  : (qi == 2) ? a2  : a3;
            float d2 = (sqq + sqc) - 2.0f * acc;
            unsigned int u = __float_as_uint(d2);
            u ^= (u & 0x80000000u) ? 0xFFFFFFFFu : 0x80000000u;
            unsigned long long key =
                ((unsigned long long)u << 32) | (unsigned int)c;
            if (!valid || c == q0 + qi) key = ~0ULL;
            if      (qi == 0) insert_top(run0, key, lane);
            else if (qi == 1) insert_top(run1, key, lane);
            else if (qi == 2) insert_top(run2, key, lane);
            else              insert_top(run3, key, lane);
        }
    }

    if (lane < K_NBR) {
        NBR[(size_t)(q0 + 0) * K_NBR + lane] = (int)(run0 & 0xFFFFFFFFULL);
        NBR[(size_t)(q0 + 1) * K_NBR + lane] = (int)(run1 & 0xFFFFFFFFULL);
        NBR[(size_t)(q0 + 2) * K_NBR + lane] = (int)(run2 & 0xFFFFFFFFULL);
        NBR[(size_t)(q0 + 3) * K_NBR + lane] = (int)(run3 & 0xFFFFFFFFULL);
    }
}

// ---------- kernel 4: fused GCN layer ----------
// By linearity: silu( ((x_i + sum_nbr x_j)/33) @ W + b ). One kernel per layer.
__global__ void gcn_fused(const float* __restrict__ Xin, const int* __restrict__ NBR,
                          const float* __restrict__ W, const float* __restrict__ bias,
                          float* __restrict__ Xout) {
    __shared__ float Ws[D_DIM * D_DIM];
    __shared__ float sAgg[8][D_DIM];
    __shared__ int nb[8][K_NBR];
    int t = threadIdx.x, g = t >> 5, d = t & 31;
    #pragma unroll
    for (int q = 0; q < 4; ++q) Ws[q * 256 + t] = W[q * 256 + t];
    int i = blockIdx.x * 8 + g;
    nb[g][d] = NBR[i * K_NBR + d];
    __syncthreads();
    float s = Xin[i * D_DIM + d];
    #pragma unroll 8
    for (int e = 0; e < K_NBR; ++e) s += Xin[nb[g][e] * D_DIM + d];
    sAgg[g][d] = s;
    __syncthreads();
    float acc = 0.f;
    #pragma unroll
    for (int m = 0; m < D_DIM; ++m)
        acc = fmaf(sAgg[g][m], Ws[m * D_DIM + d], acc);
    float v = fmaf(acc, 1.0f / 33.0f, bias[d]);   // deg == 33 for every node
    Xout[i * D_DIM + d] = silu_f(v);
}

// ---------- kernel 5: fused out-proj + aggregate + softmax ----------
__global__ void out_final(const float* __restrict__ Xin, const int* __restrict__ NBR,
                          const float* __restrict__ Wout, const float* __restrict__ out_b,
                          float* __restrict__ out) {
    __shared__ float Ws[D_DIM * 3];
    __shared__ float sAgg[8][D_DIM];
    __shared__ int nb[8][K_NBR];
    int t = threadIdx.x, g = t >> 5, d = t & 31;
    if (t < D_DIM * 3) Ws[t] = Wout[t];
    int i = blockIdx.x * 8 + g;
    nb[g][d] = NBR[i * K_NBR + d];
    __syncthreads();
    float s = Xin[i * D_DIM + d];
    #pragma unroll 8
    for (int e = 0; e < K_NBR; ++e) s += Xin[nb[g][e] * D_DIM + d];
    sAgg[g][d] = s;
    __syncthreads();
    if (d < 3) {
        float v[3];
        #pragma unroll
        for (int c = 0; c < 3; ++c) {
            float a = 0.f;
            #pragma unroll
            for (int m = 0; m < D_DIM; ++m) a = fmaf(sAgg[g][m], Ws[m * 3 + c], a);
            v[c] = fmaf(a, 1.0f / 33.0f, out_b[c]);
        }
        float mx = fmaxf(v[0], fmaxf(v[1], v[2]));
        float e0 = expf(v[0] - mx), e1 = expf(v[1] - mx), e2 = expf(v[2] - mx);
        out[i * 3 + d] = expf(v[d] - mx) / (e0 + e1 + e2);
    }
}

extern "C" void kernel_launch(void* const* d_in, const int* in_sizes, int n_in,
                              void* d_out, int out_size, void* d_ws, size_t ws_size,
                              hipStream_t stream) {
    const float* pop    = (const float*)d_in[0];
    const float* conv_w = (const float*)d_in[1];
    const float* conv_b = (const float*)d_in[2];
    const float* gamma  = (const float*)d_in[3];
    const float* beta   = (const float*)d_in[4];
    const float* gcn_ws = (const float*)d_in[5];
    const float* gcn_bs = (const float*)d_in[6];
    const float* out_w  = (const float*)d_in[7];
    const float* out_b  = (const float*)d_in[8];

    char* ws = (char*)d_ws;
    const size_t o_stats = 0;
    const size_t o_X     = 256;
    const size_t o_SQ    = o_X + 1280000;
    const size_t o_H     = o_SQ + 40192;
    const size_t o_NBR   = o_H + 1280000;

    float* stats = (float*)(ws + o_stats);
    float* X     = (float*)(ws + o_X);
    float* SQ    = (float*)(ws + o_SQ);
    float* H     = (float*)(ws + o_H);
    int*   NBR   = (int*)  (ws + o_NBR);
    float* out   = (float*)d_out;

    (void)hipMemsetAsync(stats, 0, 2 * sizeof(float), stream);
    stats_kernel<<<512, 256, 0, stream>>>(pop, stats);
    feat_kernel<<<N_NODES, 256, 0, stream>>>(pop, conv_w, conv_b, gamma, beta, stats, X, SQ);

    knn_wave<<<N_NODES / 16, 256, 0, stream>>>(X, SQ, NBR);   // 625 blocks

    gcn_fused<<<N_NODES / 8, 256, 0, stream>>>(X, NBR, gcn_ws,        gcn_bs,      H);
    gcn_fused<<<N_NODES / 8, 256, 0, stream>>>(H, NBR, gcn_ws + 1024, gcn_bs + 32, X);
    gcn_fused<<<N_NODES / 8, 256, 0, stream>>>(X, NBR, gcn_ws + 2048, gcn_bs + 64, H);
    out_final<<<N_NODES / 8, 256, 0, stream>>>(H, NBR, out_w, out_b, out);
}